// Round 3
// baseline (63.380 us; speedup 1.0000x reference)
//
#include <hip/hip_runtime.h>

#define NA 512
#define NB 128
#define OUTSTRIDE (3 * NA + 1)      // 1537 floats per batch row
// skew: j -> j + 4*(j>>6). Chunk c (64 floats) at words [c*68, c*68+64):
// 16B-aligned, contiguous within chunk; 8 chunks hit disjoint bank quads,
// row-groups read identical addresses (broadcast). Conflict-free.
#define SW(j) ((j) + ((((j) >> 6)) << 2))

__device__ __forceinline__ void accum(float f, float X, float Y, float Z,
                                      float cix, float ciy, float ciz,
                                      float& fx, float& fy, float& fz, float& ep) {
    float d  = fmaf(f, 200.0f, -100.0f);
    float dx = cix - X;
    float dy = ciy - Y;
    float dz = ciz - Z;
    float r2 = fmaf(dx, dx, fmaf(dy, dy, dz * dz));
    float rinv = (r2 > 0.f) ? rsqrtf(r2) : 0.f;   // diagonal -> 0 (diff==0 there)
    float s = d * rinv;
    fx = fmaf(s, dx, fx);
    fy = fmaf(s, dy, fy);
    fz = fmaf(s, dz, fz);
    ep += s;
}

// Block = 256 threads = 4 waves; block handles batch b, 32 consecutive rows.
// Wave w: rows rg*32 + w*8..+8. Lane: isub = lane>>3 (row), c = lane&7 (64-j chunk).
// All 16 float4 FE loads issued up front -> 16 KB/wave in flight.
__global__ __launch_bounds__(256, 4) void eij_main(const float* __restrict__ fe,
                                                   const float* __restrict__ coords,
                                                   float* __restrict__ out,
                                                   float* __restrict__ ws) {
    const int b    = blockIdx.x >> 4;    // 16 row-groups per batch
    const int rg   = blockIdx.x & 15;
    const int w    = threadIdx.x >> 6;
    const int lane = threadIdx.x & 63;
    const int isub = lane >> 3;
    const int c    = lane & 7;

    __shared__ __align__(16) float sx[544];
    __shared__ __align__(16) float sy[544];
    __shared__ __align__(16) float sz[544];
    __shared__ float sE[4];

    // Stage coords[b] (512 x 3) into skewed SoA LDS.
    const float* cb = coords + (size_t)b * (NA * 3);
    for (int t = threadIdx.x; t < NA * 3; t += 256) {
        int j = t / 3;
        int comp = t - 3 * j;
        float v = cb[t];
        int s = SW(j);
        if (comp == 0) sx[s] = v;
        else if (comp == 1) sy[s] = v;
        else sz[s] = v;
    }
    __syncthreads();

    const int i  = rg * 32 + w * 8 + isub;
    const int si = SW(i);
    const float cix = sx[si], ciy = sy[si], ciz = sz[si];

    // Issue ALL 16 global loads first (max MLP: 16 x 1KB per wave in flight).
    const float4* rowp = (const float4*)(fe + ((size_t)(b * NA + i)) * NA + c * 64);
    float4 f[16];
    #pragma unroll
    for (int t4 = 0; t4 < 16; ++t4) f[t4] = rowp[t4];

    const int cbase = c * 68;
    float fx = 0.f, fy = 0.f, fz = 0.f, ep = 0.f;
    #pragma unroll
    for (int t4 = 0; t4 < 16; ++t4) {
        const float4 X = *(const float4*)(&sx[cbase + t4 * 4]);
        const float4 Y = *(const float4*)(&sy[cbase + t4 * 4]);
        const float4 Z = *(const float4*)(&sz[cbase + t4 * 4]);
        accum(f[t4].x, X.x, Y.x, Z.x, cix, ciy, ciz, fx, fy, fz, ep);
        accum(f[t4].y, X.y, Y.y, Z.y, cix, ciy, ciz, fx, fy, fz, ep);
        accum(f[t4].z, X.z, Y.z, Z.z, cix, ciy, ciz, fx, fy, fz, ep);
        accum(f[t4].w, X.w, Y.w, Z.w, cix, ciy, ciz, fx, fy, fz, ep);
    }

    // Reduce F across the 8 j-chunks (lanes xor 1,2,4 within each row group).
    #pragma unroll
    for (int off = 1; off <= 4; off <<= 1) {
        fx += __shfl_xor(fx, off);
        fy += __shfl_xor(fy, off);
        fz += __shfl_xor(fz, off);
        ep += __shfl_xor(ep, off);
    }

    if (c == 0) {
        float* ob = out + (size_t)b * OUTSTRIDE;
        ob[i * 3 + 0] = fx;
        ob[i * 3 + 1] = fy;
        ob[i * 3 + 2] = fz;
    }

    // Finish E reduction: across row groups, then across waves via LDS.
    #pragma unroll
    for (int off = 8; off <= 32; off <<= 1)
        ep += __shfl_xor(ep, off);
    if (lane == 0) sE[w] = ep;
    __syncthreads();
    if (threadIdx.x == 0)
        ws[blockIdx.x] = sE[0] + sE[1] + sE[2] + sE[3];  // plain store, no atomic
}

// One tiny block: sum the 16 per-block partials per batch, write E.
__global__ void eij_finish(const float* __restrict__ ws, float* __restrict__ out) {
    int b = threadIdx.x;
    if (b < NB) {
        const float* p = ws + b * 16;
        float e = 0.f;
        #pragma unroll
        for (int k = 0; k < 16; ++k) e += p[k];
        out[(size_t)b * OUTSTRIDE + 3 * NA] = 0.5f * e;
    }
}

extern "C" void kernel_launch(void* const* d_in, const int* in_sizes, int n_in,
                              void* d_out, int out_size, void* d_ws, size_t ws_size,
                              hipStream_t stream) {
    const float* fe     = (const float*)d_in[0];
    const float* coords = (const float*)d_in[1];
    float* out          = (float*)d_out;
    float* ws           = (float*)d_ws;

    hipLaunchKernelGGL(eij_main, dim3(NB * 16), dim3(256), 0, stream, fe, coords, out, ws);
    hipLaunchKernelGGL(eij_finish, dim3(1), dim3(128), 0, stream, ws, out);
}